// Round 1
// baseline (1023.020 us; speedup 1.0000x reference)
//
#include <hip/hip_runtime.h>

// ---------------------------------------------------------------------------
// Problem: B=4, N=16384, DIM=512, HEADS=8, DHEAD=64, window=128
//   q = LN(y@Wq^T)*gq+bq ; k = LN(x@Wk^T)*gk+bk ; v = x@Wv^T
//   per (window,head): attn = softmax(q k^T / 8) ; ctx = attn v
//   y_new = y + ctx@Wout^T + bout
// Outputs: y_new [4,16384,512] fp32 then attn [512,8,128,128] fp32.
//
// This revision: MFMA operand-swap everywhere so each thread owns 4
// CONSECUTIVE output columns -> vectorized epilogues (float4 / packed-us4
// stores, float4 yres/bias loads). K+V projections fused into one N=1024
// GEMM (reads x-bf16 once). Softmax reduce is 2 shuffles (xor 16/32).
// ---------------------------------------------------------------------------

typedef __attribute__((ext_vector_type(8))) short short8;     // 8 bf16 (4 VGPR)
typedef __attribute__((ext_vector_type(4))) float f32x4;      // MFMA C/D
typedef __attribute__((ext_vector_type(4))) unsigned short us4;
typedef __attribute__((ext_vector_type(8))) unsigned short us8;
typedef __attribute__((ext_vector_type(4))) float fv4;

__device__ __forceinline__ unsigned short f2bf(float f) {
  unsigned u = __builtin_bit_cast(unsigned, f);
  u += 0x7fffu + ((u >> 16) & 1u);          // RNE
  return (unsigned short)(u >> 16);
}
__device__ __forceinline__ float bf2f(unsigned short h) {
  unsigned u = ((unsigned)h) << 16;
  return __builtin_bit_cast(float, u);
}

// ---------------------------------------------------------------------------
// fp32 -> bf16 convert (vectorized, 4 elems/thread)
// ---------------------------------------------------------------------------
__global__ __launch_bounds__(256) void cvt_kernel(const float* __restrict__ src,
                                                  unsigned short* __restrict__ dst,
                                                  int n4) {
  int i = blockIdx.x * 256 + threadIdx.x;
  if (i >= n4) return;
  fv4 f = *(const fv4*)(src + (size_t)i * 4);
  us4 o;
  o[0] = f2bf(f[0]); o[1] = f2bf(f[1]); o[2] = f2bf(f[2]); o[3] = f2bf(f[3]);
  *(us4*)(dst + (size_t)i * 4) = o;
}

// ---------------------------------------------------------------------------
// BT-GEMM: C[m][n] = sum_k A[m][k] * Bw[n][k],  M x Nt x 512, bf16 inputs.
// 128x128 block tile, BK=32, 256 threads (4 waves, 64x64 wave tiles).
// Staging via global_load_lds width=16 with XOR-swizzled 16B chunks so
// fragment ds_read_b128 is 2-way (free) instead of 8-way conflicted.
// MFMA operands SWAPPED: D[row=n-part(quad*4+r)][col=m-part(l16)] so a
// thread holds 4 consecutive n -> vector stores.
// FINAL=0: bf16 out (packed us4). FINAL=1: fp32 out = acc + yres + bias,
// float4 loads/stores (fused epilogue). ldc = C row stride (elems).
// ---------------------------------------------------------------------------
template <int FINAL>
__global__ __launch_bounds__(256) void gemm_bt(const unsigned short* __restrict__ A,
                                               const unsigned short* __restrict__ Bw,
                                               unsigned short* __restrict__ Cb,
                                               float* __restrict__ Cf,
                                               const float* __restrict__ yres,
                                               const float* __restrict__ bias,
                                               int ldc) {
  __shared__ __align__(16) unsigned short As[128 * 32];
  __shared__ __align__(16) unsigned short Bs[128 * 32];
  const int tid = threadIdx.x;
  const int lane = tid & 63;
  const int wv = tid >> 6;
  const int quad = lane >> 4;
  const int l16 = lane & 15;
  const size_t m0 = (size_t)blockIdx.x * 128;
  const int n0 = blockIdx.y * 128;
  const int wm = (wv >> 1) * 64;
  const int wn = (wv & 1) * 64;

  f32x4 acc[4][4];
#pragma unroll
  for (int i = 0; i < 4; i++)
#pragma unroll
    for (int j = 0; j < 4; j++) acc[i][j] = (f32x4){0.f, 0.f, 0.f, 0.f};

  // staging map: lds chunk c = i*256+tid holds global chunk (m = c>>2,
  // kc = (c&3) ^ ((m>>2)&3))  -> fragment reads become 2-way-bank-free
  int ma[2], koff[2];
#pragma unroll
  for (int i = 0; i < 2; i++) {
    int c = i * 256 + tid;
    int m = c >> 2;
    int kc = (c & 3) ^ ((m >> 2) & 3);
    ma[i] = m;
    koff[i] = kc * 16;
  }
  const char* Ab = (const char*)A;
  const char* Bb = (const char*)Bw;
  char* AsB = (char*)As;
  char* BsB = (char*)Bs;

  for (int ks = 0; ks < 512; ks += 32) {
#pragma unroll
    for (int i = 0; i < 2; i++) {
      const char* ga = Ab + ((m0 + (size_t)ma[i]) << 10) + ks * 2 + koff[i];
      const char* gb = Bb + (((size_t)(n0 + ma[i])) << 10) + ks * 2 + koff[i];
      __builtin_amdgcn_global_load_lds(
          (const __attribute__((address_space(1))) unsigned int*)ga,
          (__attribute__((address_space(3))) unsigned int*)(AsB + i * 4096 + wv * 1024),
          16, 0, 0);
      __builtin_amdgcn_global_load_lds(
          (const __attribute__((address_space(1))) unsigned int*)gb,
          (__attribute__((address_space(3))) unsigned int*)(BsB + i * 4096 + wv * 1024),
          16, 0, 0);
    }
    __syncthreads();  // drains vmcnt (DMA deposits visible), syncs waves

    short8 af[4], bf[4];
#pragma unroll
    for (int t = 0; t < 4; t++) {
      int m = wm + t * 16 + l16;
      af[t] = *(const short8*)&As[m * 32 + ((quad ^ ((m >> 2) & 3)) * 8)];
      int n = wn + t * 16 + l16;
      bf[t] = *(const short8*)&Bs[n * 32 + ((quad ^ ((n >> 2) & 3)) * 8)];
    }
    // swapped: A-operand = bf (free dim n), B-operand = af (free dim m)
#pragma unroll
    for (int mt = 0; mt < 4; mt++)
#pragma unroll
      for (int nt = 0; nt < 4; nt++)
        acc[mt][nt] =
            __builtin_amdgcn_mfma_f32_16x16x32_bf16(bf[nt], af[mt], acc[mt][nt], 0, 0, 0);
    __syncthreads();  // all reads done before next stage overwrites
  }

  // epilogue; swapped C/D layout: m = l16, n = quad*4 + r (4 consecutive n)
#pragma unroll
  for (int mt = 0; mt < 4; mt++) {
    size_t m = m0 + wm + mt * 16 + l16;
#pragma unroll
    for (int nt = 0; nt < 4; nt++) {
      int n = n0 + wn + nt * 16 + quad * 4;
      size_t idx = m * (size_t)ldc + n;
      if (FINAL) {
        fv4 yv = *(const fv4*)(yres + idx);
        fv4 bv = *(const fv4*)(bias + n);
        fv4 o;
#pragma unroll
        for (int r = 0; r < 4; r++) o[r] = acc[mt][nt][r] + yv[r] + bv[r];
        *(fv4*)(Cf + idx) = o;
      } else {
        us4 o;
#pragma unroll
        for (int r = 0; r < 4; r++) o[r] = f2bf(acc[mt][nt][r]);
        *(us4*)(Cb + idx) = o;
      }
    }
  }
}

// ---------------------------------------------------------------------------
// In-place LayerNorm over rows of 512 bf16 (row stride = ld elems).
// One wave per row (8 elems/lane).
// ---------------------------------------------------------------------------
__global__ __launch_bounds__(256) void ln_rows(unsigned short* __restrict__ t,
                                               const float* __restrict__ g,
                                               const float* __restrict__ b,
                                               int ld) {
  size_t row = (size_t)blockIdx.x * 4 + (threadIdx.x >> 6);
  int lane = threadIdx.x & 63;
  unsigned short* p = t + row * (size_t)ld + lane * 8;
  us8 raw = *(const us8*)p;
  float v[8];
#pragma unroll
  for (int i = 0; i < 8; i++) v[i] = bf2f(raw[i]);
  float s = 0.f;
#pragma unroll
  for (int i = 0; i < 8; i++) s += v[i];
#pragma unroll
  for (int off = 32; off; off >>= 1) s += __shfl_xor(s, off);
  float mean = s * (1.0f / 512.0f);
  float qs = 0.f;
#pragma unroll
  for (int i = 0; i < 8; i++) {
    float d = v[i] - mean;
    qs += d * d;
  }
#pragma unroll
  for (int off = 32; off; off >>= 1) qs += __shfl_xor(qs, off);
  float rstd = rsqrtf(qs * (1.0f / 512.0f) + 1e-5f);
  const float* gp = g + lane * 8;
  const float* bp = b + lane * 8;
  us8 o;
#pragma unroll
  for (int i = 0; i < 8; i++) o[i] = f2bf((v[i] - mean) * rstd * gp[i] + bp[i]);
  *(us8*)p = o;
}

// ---------------------------------------------------------------------------
// Attention: one WG per (head h = blockIdx.x, window bw = blockIdx.y).
// 256 threads = 4 waves; wave handles a 32-row strip of the 128x128 score.
// QK^T SWAPPED (mfma(k, q)) -> lane holds, for its q-row i=l16, the score
// slice j = ni*16 + quad*4 + r. Softmax row-reduce = 2 shuffles (xor16/32).
// attn_out written as float4; P packed to LDS as us4 (swizzled chunks).
// PV SWAPPED (mfma(vT, P)) -> ctx packed us4 stores.
// K/V live in a fused buffer with row stride 1024 (K at +0, V at +512).
// ---------------------------------------------------------------------------
#define KVLD 1024

__global__ __launch_bounds__(256) void attn_kernel(const unsigned short* __restrict__ q,
                                                   const unsigned short* __restrict__ kmat,
                                                   const unsigned short* __restrict__ v,
                                                   float* __restrict__ attn_out,
                                                   unsigned short* __restrict__ ctx) {
  __shared__ __align__(16) unsigned short vT[64 * 128];   // [d][t], swizzled 16B chunks
  __shared__ __align__(16) unsigned short Ps[128 * 128];  // [i][j], swizzled 16B chunks
  const int h = blockIdx.x;
  const int bw = blockIdx.y;
  const int tb = bw * 128;  // global token base of this window
  const int tid = threadIdx.x;
  const int lane = tid & 63;
  const int wv = tid >> 6;
  const int quad = lane >> 4;
  const int l16 = lane & 15;
  const int hoff = h * 64;

  // ---- stage v transposed: vT[d][t] = v[tb+t][hoff+d]
#pragma unroll
  for (int it = 0; it < 8; it++) {
    int idx = (it * 256 + tid) * 4;  // 0..8188, 4 consecutive d per thread
    int t = idx >> 6;
    int d = idx & 63;
    us4 val = *(const us4*)&v[(size_t)(tb + t) * KVLD + hoff + d];
#pragma unroll
    for (int j = 0; j < 4; j++) {
      int dd = d + j;
      int cp = (t >> 3) ^ (dd & 15);
      vT[dd * 128 + cp * 8 + (t & 7)] = val[j];
    }
  }

  // ---- S = q k^T, swapped: acc[mi][ni] = D[j-part][i-part]
  f32x4 acc[2][8];
#pragma unroll
  for (int mi = 0; mi < 2; mi++)
#pragma unroll
    for (int ni = 0; ni < 8; ni++) acc[mi][ni] = (f32x4){0.f, 0.f, 0.f, 0.f};

  short8 aq[2][2];
#pragma unroll
  for (int mi = 0; mi < 2; mi++) {
    int tok = tb + wv * 32 + mi * 16 + l16;
#pragma unroll
    for (int kk = 0; kk < 2; kk++)
      aq[mi][kk] = *(const short8*)&q[(size_t)tok * 512 + hoff + kk * 32 + quad * 8];
  }
#pragma unroll
  for (int ni = 0; ni < 8; ni++) {
    int ktok = tb + ni * 16 + l16;
    short8 bk0 = *(const short8*)&kmat[(size_t)ktok * KVLD + hoff + quad * 8];
    short8 bk1 = *(const short8*)&kmat[(size_t)ktok * KVLD + hoff + 32 + quad * 8];
#pragma unroll
    for (int mi = 0; mi < 2; mi++) {
      acc[mi][ni] = __builtin_amdgcn_mfma_f32_16x16x32_bf16(bk0, aq[mi][0], acc[mi][ni], 0, 0, 0);
      acc[mi][ni] = __builtin_amdgcn_mfma_f32_16x16x32_bf16(bk1, aq[mi][1], acc[mi][ni], 0, 0, 0);
    }
  }

  // ---- softmax over rows; lane owns row i = wv*32+mi*16+l16, cols
  // j = ni*16 + quad*4 + r (32 values). Cross-quad reduce: xor 16, 32.
  size_t abase = ((size_t)(bw * 8 + h)) << 14;  // *16384
#pragma unroll
  for (int mi = 0; mi < 2; mi++) {
    float mx = acc[mi][0][0];
#pragma unroll
    for (int ni = 0; ni < 8; ni++)
#pragma unroll
      for (int r = 0; r < 4; r++) mx = fmaxf(mx, acc[mi][ni][r]);
    mx = fmaxf(mx, __shfl_xor(mx, 16));
    mx = fmaxf(mx, __shfl_xor(mx, 32));
    float pv[8][4];
    float sum = 0.f;
#pragma unroll
    for (int ni = 0; ni < 8; ni++)
#pragma unroll
      for (int r = 0; r < 4; r++) {
        pv[ni][r] = __expf((acc[mi][ni][r] - mx) * 0.125f);
        sum += pv[ni][r];
      }
    sum += __shfl_xor(sum, 16);
    sum += __shfl_xor(sum, 32);
    float inv = 1.0f / sum;
    int i = wv * 32 + mi * 16 + l16;
    int cpx = (i & 15);
#pragma unroll
    for (int ni = 0; ni < 8; ni++) {
      int j0 = ni * 16 + quad * 4;
      fv4 pq;
      us4 pb;
#pragma unroll
      for (int r = 0; r < 4; r++) {
        float p = pv[ni][r] * inv;
        pq[r] = p;
        pb[r] = f2bf(p);
      }
      *(fv4*)&attn_out[abase + (size_t)i * 128 + j0] = pq;
      int cp = (j0 >> 3) ^ cpx;
      *(us4*)&Ps[i * 128 + cp * 8 + (quad & 1) * 4] = pb;
    }
  }
  __syncthreads();  // Ps + vT ready for all waves

  // ---- ctx = P @ v, swapped: D[d-part][i-part]
  f32x4 o[2][4];
#pragma unroll
  for (int mi = 0; mi < 2; mi++)
#pragma unroll
    for (int nt = 0; nt < 4; nt++) o[mi][nt] = (f32x4){0.f, 0.f, 0.f, 0.f};

#pragma unroll
  for (int ks = 0; ks < 4; ks++) {
    short8 vfr[4];
#pragma unroll
    for (int nt = 0; nt < 4; nt++) {
      int d = nt * 16 + l16;
      int cp = (ks * 4 + quad) ^ (d & 15);
      vfr[nt] = *(const short8*)&vT[d * 128 + cp * 8];
    }
#pragma unroll
    for (int mi = 0; mi < 2; mi++) {
      int i = wv * 32 + mi * 16 + l16;
      int cp = (ks * 4 + quad) ^ (i & 15);
      short8 pfr = *(const short8*)&Ps[i * 128 + cp * 8];
#pragma unroll
      for (int nt = 0; nt < 4; nt++)
        o[mi][nt] = __builtin_amdgcn_mfma_f32_16x16x32_bf16(vfr[nt], pfr, o[mi][nt], 0, 0, 0);
    }
  }
  // store: i = wv*32+mi*16+l16 ; d = nt*16 + quad*4 + r (4 consecutive)
#pragma unroll
  for (int mi = 0; mi < 2; mi++) {
    int tok = tb + wv * 32 + mi * 16 + l16;
#pragma unroll
    for (int nt = 0; nt < 4; nt++) {
      int d0 = nt * 16 + quad * 4;
      us4 ov;
#pragma unroll
      for (int r = 0; r < 4; r++) ov[r] = f2bf(o[mi][nt][r]);
      *(us4*)&ctx[(size_t)tok * 512 + hoff + d0] = ov;
    }
  }
}

// ---------------------------------------------------------------------------
extern "C" void kernel_launch(void* const* d_in, const int* in_sizes, int n_in,
                              void* d_out, int out_size, void* d_ws, size_t ws_size,
                              hipStream_t stream) {
  const float* x = (const float*)d_in[0];
  const float* y = (const float*)d_in[1];
  const float* Wq = (const float*)d_in[2];
  const float* gq = (const float*)d_in[3];
  const float* bq = (const float*)d_in[4];
  const float* Wk = (const float*)d_in[5];
  const float* gk = (const float*)d_in[6];
  const float* bk = (const float*)d_in[7];
  const float* Wv = (const float*)d_in[8];
  const float* Wout = (const float*)d_in[9];
  const float* bout = (const float*)d_in[10];
  float* out = (float*)d_out;

  // workspace layout (bytes)
  char* ws = (char*)d_ws;
  const size_t W = 524288;     // 512*512 bf16
  const size_t T = 67108864;   // 65536*512 bf16
  unsigned short* WQB = (unsigned short*)(ws);              // [512][512]
  unsigned short* WKVB = (unsigned short*)(ws + W);         // [1024][512] = Wk;Wv
  unsigned short* WOB = (unsigned short*)(ws + 3 * W);      // [512][512]
  unsigned short* XB = (unsigned short*)(ws + 4 * W);       // x bf16
  unsigned short* YB = (unsigned short*)(ws + 4 * W + T);   // y bf16; reused as ctx
  unsigned short* Q = (unsigned short*)(ws + 4 * W + 2 * T);
  unsigned short* KV = (unsigned short*)(ws + 4 * W + 3 * T);  // [65536][1024]
  unsigned short* CTX = YB;  // alias: yb dead after q-projection GEMM

  // bf16 conversions
  cvt_kernel<<<256, 256, 0, stream>>>(Wq, WQB, 65536);
  cvt_kernel<<<256, 256, 0, stream>>>(Wk, WKVB, 65536);
  cvt_kernel<<<256, 256, 0, stream>>>(Wv, WKVB + 262144, 65536);
  cvt_kernel<<<256, 256, 0, stream>>>(Wout, WOB, 65536);
  cvt_kernel<<<32768, 256, 0, stream>>>(x, XB, 8388608);
  cvt_kernel<<<32768, 256, 0, stream>>>(y, YB, 8388608);

  // projections: Q (M=65536,N=512), fused KV (M=65536,N=1024, one x pass)
  gemm_bt<0><<<dim3(512, 4), 256, 0, stream>>>(YB, WQB, Q, nullptr, nullptr, nullptr, 512);
  gemm_bt<0><<<dim3(512, 8), 256, 0, stream>>>(XB, WKVB, KV, nullptr, nullptr, nullptr, 1024);

  // layernorms (in-place on bf16); K = first 512 cols of KV rows
  ln_rows<<<16384, 256, 0, stream>>>(Q, gq, bq, 512);
  ln_rows<<<16384, 256, 0, stream>>>(KV, gk, bk, 1024);

  // attention: attn -> d_out (after y_new region), ctx -> ws
  attn_kernel<<<dim3(8, 512), 256, 0, stream>>>(Q, KV, KV + 512, out + 33554432, CTX);

  // y_new = y + ctx @ Wout^T + bout
  gemm_bt<1><<<dim3(512, 4), 256, 0, stream>>>(CTX, WOB, nullptr, out, y, bout, 512);
}

// Round 3
// 1020.270 us; speedup vs baseline: 1.0027x; 1.0027x over previous
//
#include <hip/hip_runtime.h>

// ---------------------------------------------------------------------------
// Problem: B=4, N=16384, DIM=512, HEADS=8, DHEAD=64, window=128
//   q = LN(y@Wq^T)*gq+bq ; k = LN(x@Wk^T)*gk+bk ; v = x@Wv^T
//   per (window,head): attn = softmax(q k^T / 8) ; ctx = attn v
//   y_new = y + ctx@Wout^T + bout
// Outputs: y_new [4,16384,512] fp32 then attn [512,8,128,128] fp32.
//
// LayerNorm passes eliminated: GEMM epilogue emits per-row (sum,sumsq)
// partials, tiny stats kernel finalizes (mean,rstd), attention normalizes
// Q/K fragments on the fly. Stats scratch lives in DEAD regions of d_out
// (y_new area, overwritten by the final GEMM) so workspace stays at the
// proven 4W+5T footprint. XCD-chunked swizzles on GEMMs and attn.
// ---------------------------------------------------------------------------

typedef __attribute__((ext_vector_type(8))) short short8;     // 8 bf16 (4 VGPR)
typedef __attribute__((ext_vector_type(4))) float f32x4;      // MFMA C/D
typedef __attribute__((ext_vector_type(4))) unsigned short us4;
typedef __attribute__((ext_vector_type(8))) unsigned short us8;
typedef __attribute__((ext_vector_type(4))) float fv4;
typedef __attribute__((ext_vector_type(2))) float fv2;

__device__ __forceinline__ unsigned short f2bf(float f) {
  unsigned u = __builtin_bit_cast(unsigned, f);
  u += 0x7fffu + ((u >> 16) & 1u);          // RNE
  return (unsigned short)(u >> 16);
}
__device__ __forceinline__ float bf2f(unsigned short h) {
  unsigned u = ((unsigned)h) << 16;
  return __builtin_bit_cast(float, u);
}

// ---------------------------------------------------------------------------
// fp32 -> bf16 convert (vectorized, 4 elems/thread)
// ---------------------------------------------------------------------------
__global__ __launch_bounds__(256) void cvt_kernel(const float* __restrict__ src,
                                                  unsigned short* __restrict__ dst,
                                                  int n4) {
  int i = blockIdx.x * 256 + threadIdx.x;
  if (i >= n4) return;
  fv4 f = *(const fv4*)(src + (size_t)i * 4);
  us4 o;
  o[0] = f2bf(f[0]); o[1] = f2bf(f[1]); o[2] = f2bf(f[2]); o[3] = f2bf(f[3]);
  *(us4*)(dst + (size_t)i * 4) = o;
}

// 4 weight tensors (512x512 each) in one launch; blockIdx.y selects tensor.
__global__ __launch_bounds__(256) void cvt4_kernel(const float* __restrict__ s0,
                                                   const float* __restrict__ s1,
                                                   const float* __restrict__ s2,
                                                   const float* __restrict__ s3,
                                                   unsigned short* __restrict__ d0,
                                                   unsigned short* __restrict__ d1,
                                                   unsigned short* __restrict__ d2,
                                                   unsigned short* __restrict__ d3) {
  const float* s;
  unsigned short* d;
  switch (blockIdx.y) {
    case 0: s = s0; d = d0; break;
    case 1: s = s1; d = d1; break;
    case 2: s = s2; d = d2; break;
    default: s = s3; d = d3; break;
  }
  int i = blockIdx.x * 256 + threadIdx.x;  // 65536 fv4 per tensor
  fv4 f = *(const fv4*)(s + (size_t)i * 4);
  us4 o;
  o[0] = f2bf(f[0]); o[1] = f2bf(f[1]); o[2] = f2bf(f[2]); o[3] = f2bf(f[3]);
  *(us4*)(d + (size_t)i * 4) = o;
}

// ---------------------------------------------------------------------------
// BT-GEMM: C[m][n] = sum_k A[m][k] * Bw[n][k],  M x Nt x 512, bf16 inputs.
// 128x128 block tile, BK=32, 256 threads (4 waves, 64x64 wave tiles).
// Staging via global_load_lds width=16, XOR-swizzled 16B chunks.
// MFMA operands swapped: thread holds 4 consecutive n -> vector stores.
// XCD-chunked swizzle: contiguous chunk per XCD, n-fastest within chunk so
// the 128KB A-panel stays L2-resident across its n-blocks.
// LNS=1: epilogue also writes per-row (sum,sumsq) partials (n0<512 only).
// FINAL=1: fp32 out = acc + yres + bias (fused residual epilogue).
// ---------------------------------------------------------------------------
template <int FINAL, int LNS>
__global__ __launch_bounds__(256) void gemm_bt(const unsigned short* __restrict__ A,
                                               const unsigned short* __restrict__ Bw,
                                               unsigned short* __restrict__ Cb,
                                               float* __restrict__ Cf,
                                               const float* __restrict__ yres,
                                               const float* __restrict__ bias,
                                               int ldc,
                                               fv2* __restrict__ pstat) {
  __shared__ __align__(16) unsigned short As[128 * 32];
  __shared__ __align__(16) unsigned short Bs[128 * 32];
  const int tid = threadIdx.x;
  const int lane = tid & 63;
  const int wv = tid >> 6;
  const int quad = lane >> 4;
  const int l16 = lane & 15;

  // XCD-chunked bijective swizzle (nwg = gridDim.x * gy, multiple of 8)
  const int gy = gridDim.y;                    // 4 or 8 (power of 2)
  const int sh = (gy == 8) ? 3 : 2;
  const int nwg = (int)gridDim.x << sh;
  const int hwid = blockIdx.y * gridDim.x + blockIdx.x;
  const int w = (hwid & 7) * (nwg >> 3) + (hwid >> 3);
  const size_t m0 = (size_t)(w >> sh) * 128;   // m-major
  const int n0 = (w & (gy - 1)) * 128;         // n-fastest within chunk

  const int wm = (wv >> 1) * 64;
  const int wn = (wv & 1) * 64;

  f32x4 acc[4][4];
#pragma unroll
  for (int i = 0; i < 4; i++)
#pragma unroll
    for (int j = 0; j < 4; j++) acc[i][j] = (f32x4){0.f, 0.f, 0.f, 0.f};

  // staging map: lds chunk c = i*256+tid holds global chunk (m = c>>2,
  // kc = (c&3) ^ ((m>>2)&3))  -> fragment reads become 2-way-bank-free
  int ma[2], koff[2];
#pragma unroll
  for (int i = 0; i < 2; i++) {
    int c = i * 256 + tid;
    int m = c >> 2;
    int kc = (c & 3) ^ ((m >> 2) & 3);
    ma[i] = m;
    koff[i] = kc * 16;
  }
  const char* Ab = (const char*)A;
  const char* Bb = (const char*)Bw;
  char* AsB = (char*)As;
  char* BsB = (char*)Bs;

  for (int ks = 0; ks < 512; ks += 32) {
#pragma unroll
    for (int i = 0; i < 2; i++) {
      const char* ga = Ab + ((m0 + (size_t)ma[i]) << 10) + ks * 2 + koff[i];
      const char* gb = Bb + (((size_t)(n0 + ma[i])) << 10) + ks * 2 + koff[i];
      __builtin_amdgcn_global_load_lds(
          (const __attribute__((address_space(1))) unsigned int*)ga,
          (__attribute__((address_space(3))) unsigned int*)(AsB + i * 4096 + wv * 1024),
          16, 0, 0);
      __builtin_amdgcn_global_load_lds(
          (const __attribute__((address_space(1))) unsigned int*)gb,
          (__attribute__((address_space(3))) unsigned int*)(BsB + i * 4096 + wv * 1024),
          16, 0, 0);
    }
    __syncthreads();  // drains vmcnt (DMA deposits visible), syncs waves

    short8 af[4], bf[4];
#pragma unroll
    for (int t = 0; t < 4; t++) {
      int m = wm + t * 16 + l16;
      af[t] = *(const short8*)&As[m * 32 + ((quad ^ ((m >> 2) & 3)) * 8)];
      int n = wn + t * 16 + l16;
      bf[t] = *(const short8*)&Bs[n * 32 + ((quad ^ ((n >> 2) & 3)) * 8)];
    }
    // swapped: A-operand = bf (free dim n), B-operand = af (free dim m)
#pragma unroll
    for (int mt = 0; mt < 4; mt++)
#pragma unroll
      for (int nt = 0; nt < 4; nt++)
        acc[mt][nt] =
            __builtin_amdgcn_mfma_f32_16x16x32_bf16(bf[nt], af[mt], acc[mt][nt], 0, 0, 0);
    __syncthreads();  // all reads done before next stage overwrites
  }

  // epilogue; swapped C/D layout: m = l16, n = quad*4 + r (4 consecutive n)
#pragma unroll
  for (int mt = 0; mt < 4; mt++) {
    size_t m = m0 + wm + mt * 16 + l16;
#pragma unroll
    for (int nt = 0; nt < 4; nt++) {
      int n = n0 + wn + nt * 16 + quad * 4;
      size_t idx = m * (size_t)ldc + n;
      if (FINAL) {
        fv4 yv = *(const fv4*)(yres + idx);
        fv4 bv = *(const fv4*)(bias + n);
        fv4 o;
#pragma unroll
        for (int r = 0; r < 4; r++) o[r] = acc[mt][nt][r] + yv[r] + bv[r];
        *(fv4*)(Cf + idx) = o;
      } else {
        us4 o;
#pragma unroll
        for (int r = 0; r < 4; r++) o[r] = f2bf(acc[mt][nt][r]);
        *(us4*)(Cb + idx) = o;
      }
    }
  }

  // LN partial stats: per row, sum/sumsq over this block's 128 cols.
  // Thread holds 16 cols of each of its 4 rows; quad-reduce via xor 16/32.
  if (LNS && n0 < 512) {
#pragma unroll
    for (int mt = 0; mt < 4; mt++) {
      float s = 0.f, s2 = 0.f;
#pragma unroll
      for (int nt = 0; nt < 4; nt++)
#pragma unroll
        for (int r = 0; r < 4; r++) {
          float t = acc[mt][nt][r];
          s += t;
          s2 += t * t;
        }
      s += __shfl_xor(s, 16);
      s += __shfl_xor(s, 32);
      s2 += __shfl_xor(s2, 16);
      s2 += __shfl_xor(s2, 32);
      if (quad == 0) {
        size_t row = m0 + wm + mt * 16 + l16;
        fv2 p;
        p[0] = s;
        p[1] = s2;
        pstat[row * 8 + (n0 >> 7) * 2 + (wv & 1)] = p;
      }
    }
  }
}

// ---------------------------------------------------------------------------
// Finalize LN stats: reduce 8 partials/row -> (mean, rstd). y=0: Q, y=1: K.
// ---------------------------------------------------------------------------
__global__ __launch_bounds__(256) void stats_fin(const fv2* __restrict__ pq,
                                                 const fv2* __restrict__ pk,
                                                 fv2* __restrict__ sq,
                                                 fv2* __restrict__ sk) {
  int row = blockIdx.x * 256 + threadIdx.x;
  const fv2* p = blockIdx.y ? pk : pq;
  fv2* so = blockIdx.y ? sk : sq;
  float s = 0.f, s2 = 0.f;
#pragma unroll
  for (int i = 0; i < 8; i++) {
    fv2 v = p[(size_t)row * 8 + i];
    s += v[0];
    s2 += v[1];
  }
  float mean = s * (1.0f / 512.0f);
  float var = s2 * (1.0f / 512.0f) - mean * mean;
  fv2 o;
  o[0] = mean;
  o[1] = rsqrtf(var + 1e-5f);
  so[row] = o;
}

// ---------------------------------------------------------------------------
// Attention: one WG per (head, window); XCD-chunked swizzle keeps all 8 heads
// of a window on one XCD. 256 threads = 4 waves, wave owns a 32-row strip.
// Q/K are UN-normalized bf16 projections; per-token (mean,rstd) and per-dim
// g/b applied while building MFMA fragments. QK^T swapped -> lane owns a full
// 32-col slice of its q-row; softmax reduce = 2 shuffles. P -> LDS bf16
// (swizzled); PV swapped. K/V fused buffer, row stride 1024 (K +0, V +512).
// ---------------------------------------------------------------------------
#define KVLD 1024

__global__ __launch_bounds__(256) void attn_kernel(const unsigned short* __restrict__ q,
                                                   const unsigned short* __restrict__ kmat,
                                                   const unsigned short* __restrict__ v,
                                                   const fv2* __restrict__ sq,
                                                   const fv2* __restrict__ sk,
                                                   const float* __restrict__ gq,
                                                   const float* __restrict__ bq,
                                                   const float* __restrict__ gk,
                                                   const float* __restrict__ bk,
                                                   float* __restrict__ attn_out,
                                                   unsigned short* __restrict__ ctx) {
  __shared__ __align__(16) unsigned short vT[64 * 128];   // [d][t], swizzled 16B chunks
  __shared__ __align__(16) unsigned short Ps[128 * 128];  // [i][j], swizzled 16B chunks
  // swizzle: 4096 blocks -> XCD k gets windows [k*64, (k+1)*64), h fastest
  const int hwid = blockIdx.x;
  const int wk = (hwid & 7) * 512 + (hwid >> 3);
  const int h = wk & 7;
  const int bw = wk >> 3;
  const int tb = bw * 128;  // global token base of this window
  const int tid = threadIdx.x;
  const int lane = tid & 63;
  const int wv = tid >> 6;
  const int quad = lane >> 4;
  const int l16 = lane & 15;
  const int hoff = h * 64;

  // ---- stage v transposed: vT[d][t] = v[tb+t][hoff+d]
#pragma unroll
  for (int it = 0; it < 8; it++) {
    int idx = (it * 256 + tid) * 4;  // 0..8188, 4 consecutive d per thread
    int t = idx >> 6;
    int d = idx & 63;
    us4 val = *(const us4*)&v[(size_t)(tb + t) * KVLD + hoff + d];
#pragma unroll
    for (int j = 0; j < 4; j++) {
      int dd = d + j;
      int cp = (t >> 3) ^ (dd & 15);
      vT[dd * 128 + cp * 8 + (t & 7)] = val[j];
    }
  }

  // ---- S = q k^T, swapped: acc[mi][ni] = D[j-part][i-part]
  f32x4 acc[2][8];
#pragma unroll
  for (int mi = 0; mi < 2; mi++)
#pragma unroll
    for (int ni = 0; ni < 8; ni++) acc[mi][ni] = (f32x4){0.f, 0.f, 0.f, 0.f};

  short8 aq[2][2];
#pragma unroll
  for (int mi = 0; mi < 2; mi++) {
    int tok = tb + wv * 32 + mi * 16 + l16;
    fv2 st = sq[tok];
#pragma unroll
    for (int kk = 0; kk < 2; kk++) {
      const float* gp = gq + hoff + kk * 32 + quad * 8;
      const float* bp = bq + hoff + kk * 32 + quad * 8;
      us8 raw = *(const us8*)&q[(size_t)tok * 512 + hoff + kk * 32 + quad * 8];
      us8 o;
#pragma unroll
      for (int e = 0; e < 8; e++) {
        float f = (bf2f(raw[e]) - st[0]) * st[1] * gp[e] + bp[e];
        o[e] = f2bf(f);
      }
      aq[mi][kk] = __builtin_bit_cast(short8, o);
    }
  }
#pragma unroll
  for (int ni = 0; ni < 8; ni++) {
    int ktok = tb + ni * 16 + l16;
    fv2 stk = sk[ktok];
    us8 r0 = *(const us8*)&kmat[(size_t)ktok * KVLD + hoff + quad * 8];
    us8 r1 = *(const us8*)&kmat[(size_t)ktok * KVLD + hoff + 32 + quad * 8];
    const float* g0 = gk + hoff + quad * 8;
    const float* b0 = bk + hoff + quad * 8;
    us8 o0, o1;
#pragma unroll
    for (int e = 0; e < 8; e++) {
      o0[e] = f2bf((bf2f(r0[e]) - stk[0]) * stk[1] * g0[e] + b0[e]);
      o1[e] = f2bf((bf2f(r1[e]) - stk[0]) * stk[1] * g0[32 + e] + b0[32 + e]);
    }
    short8 bk0 = __builtin_bit_cast(short8, o0);
    short8 bk1 = __builtin_bit_cast(short8, o1);
#pragma unroll
    for (int mi = 0; mi < 2; mi++) {
      acc[mi][ni] = __builtin_amdgcn_mfma_f32_16x16x32_bf16(bk0, aq[mi][0], acc[mi][ni], 0, 0, 0);
      acc[mi][ni] = __builtin_amdgcn_mfma_f32_16x16x32_bf16(bk1, aq[mi][1], acc[mi][ni], 0, 0, 0);
    }
  }

  // ---- softmax; lane owns row i = wv*32+mi*16+l16, cols j = ni*16+quad*4+r.
  size_t abase = ((size_t)(bw * 8 + h)) << 14;  // *16384
#pragma unroll
  for (int mi = 0; mi < 2; mi++) {
    float mx = acc[mi][0][0];
#pragma unroll
    for (int ni = 0; ni < 8; ni++)
#pragma unroll
      for (int r = 0; r < 4; r++) mx = fmaxf(mx, acc[mi][ni][r]);
    mx = fmaxf(mx, __shfl_xor(mx, 16));
    mx = fmaxf(mx, __shfl_xor(mx, 32));
    float pv[8][4];
    float sum = 0.f;
#pragma unroll
    for (int ni = 0; ni < 8; ni++)
#pragma unroll
      for (int r = 0; r < 4; r++) {
        pv[ni][r] = __expf((acc[mi][ni][r] - mx) * 0.125f);
        sum += pv[ni][r];
      }
    sum += __shfl_xor(sum, 16);
    sum += __shfl_xor(sum, 32);
    float inv = 1.0f / sum;
    int i = wv * 32 + mi * 16 + l16;
    int cpx = (i & 15);
#pragma unroll
    for (int ni = 0; ni < 8; ni++) {
      int j0 = ni * 16 + quad * 4;
      fv4 pq;
      us4 pb;
#pragma unroll
      for (int r = 0; r < 4; r++) {
        float p = pv[ni][r] * inv;
        pq[r] = p;
        pb[r] = f2bf(p);
      }
      *(fv4*)&attn_out[abase + (size_t)i * 128 + j0] = pq;
      int cp = (j0 >> 3) ^ cpx;
      *(us4*)&Ps[i * 128 + cp * 8 + (quad & 1) * 4] = pb;
    }
  }
  __syncthreads();  // Ps + vT ready for all waves

  // ---- ctx = P @ v, swapped: D[d-part][i-part]
  f32x4 o[2][4];
#pragma unroll
  for (int mi = 0; mi < 2; mi++)
#pragma unroll
    for (int nt = 0; nt < 4; nt++) o[mi][nt] = (f32x4){0.f, 0.f, 0.f, 0.f};

#pragma unroll
  for (int ks = 0; ks < 4; ks++) {
    short8 vfr[4];
#pragma unroll
    for (int nt = 0; nt < 4; nt++) {
      int d = nt * 16 + l16;
      int cp = (ks * 4 + quad) ^ (d & 15);
      vfr[nt] = *(const short8*)&vT[d * 128 + cp * 8];
    }
#pragma unroll
    for (int mi = 0; mi < 2; mi++) {
      int i = wv * 32 + mi * 16 + l16;
      int cp = (ks * 4 + quad) ^ (i & 15);
      short8 pfr = *(const short8*)&Ps[i * 128 + cp * 8];
#pragma unroll
      for (int nt = 0; nt < 4; nt++)
        o[mi][nt] = __builtin_amdgcn_mfma_f32_16x16x32_bf16(vfr[nt], pfr, o[mi][nt], 0, 0, 0);
    }
  }
  // store: i = wv*32+mi*16+l16 ; d = nt*16 + quad*4 + r (4 consecutive)
#pragma unroll
  for (int mi = 0; mi < 2; mi++) {
    int tok = tb + wv * 32 + mi * 16 + l16;
#pragma unroll
    for (int nt = 0; nt < 4; nt++) {
      int d0 = nt * 16 + quad * 4;
      us4 ov;
#pragma unroll
      for (int r = 0; r < 4; r++) ov[r] = f2bf(o[mi][nt][r]);
      *(us4*)&ctx[(size_t)tok * 512 + hoff + d0] = ov;
    }
  }
}

// ---------------------------------------------------------------------------
extern "C" void kernel_launch(void* const* d_in, const int* in_sizes, int n_in,
                              void* d_out, int out_size, void* d_ws, size_t ws_size,
                              hipStream_t stream) {
  const float* x = (const float*)d_in[0];
  const float* y = (const float*)d_in[1];
  const float* Wq = (const float*)d_in[2];
  const float* gq = (const float*)d_in[3];
  const float* bq = (const float*)d_in[4];
  const float* Wk = (const float*)d_in[5];
  const float* gk = (const float*)d_in[6];
  const float* bk = (const float*)d_in[7];
  const float* Wv = (const float*)d_in[8];
  const float* Wout = (const float*)d_in[9];
  const float* bout = (const float*)d_in[10];
  float* out = (float*)d_out;

  // workspace layout (bytes) — identical footprint to the proven kernel
  char* ws = (char*)d_ws;
  const size_t W = 524288;     // 512*512 bf16
  const size_t T = 67108864;   // 65536*512 bf16
  unsigned short* WQB = (unsigned short*)(ws);              // [512][512]
  unsigned short* WKVB = (unsigned short*)(ws + W);         // [1024][512] = Wk;Wv
  unsigned short* WOB = (unsigned short*)(ws + 3 * W);      // [512][512]
  unsigned short* XB = (unsigned short*)(ws + 4 * W);       // x bf16
  unsigned short* YB = (unsigned short*)(ws + 4 * W + T);   // y bf16; reused as ctx
  unsigned short* Q = (unsigned short*)(ws + 4 * W + 2 * T);
  unsigned short* KV = (unsigned short*)(ws + 4 * W + 3 * T);  // [65536][1024]
  unsigned short* CTX = YB;  // alias: yb dead after q-projection GEMM

  // LN stats scratch in DEAD d_out regions (y_new area: only written by the
  // final GEMM, which runs after all stats consumers).
  fv2* Pq = (fv2*)(out);                 // floats [0, 1048576)
  fv2* Pk = (fv2*)(out + 2097152);       // floats [2097152, 3145728)
  fv2* Sq = (fv2*)(out + 4194304);       // floats [4194304, 4325376)
  fv2* Sk = (fv2*)(out + 6291456);       // floats [6291456, 6422528)

  // bf16 conversions (weights fused to one launch)
  cvt4_kernel<<<dim3(256, 4), 256, 0, stream>>>(Wq, Wk, Wv, Wout, WQB, WKVB,
                                                WKVB + 262144, WOB);
  cvt_kernel<<<32768, 256, 0, stream>>>(x, XB, 8388608);
  cvt_kernel<<<32768, 256, 0, stream>>>(y, YB, 8388608);

  // projections: Q (M=65536,N=512), fused KV (M=65536,N=1024, one x pass).
  // Both emit per-row LN partials (K half only for the KV gemm).
  gemm_bt<0, 1><<<dim3(512, 4), 256, 0, stream>>>(YB, WQB, Q, nullptr, nullptr,
                                                  nullptr, 512, Pq);
  gemm_bt<0, 1><<<dim3(512, 8), 256, 0, stream>>>(XB, WKVB, KV, nullptr, nullptr,
                                                  nullptr, 1024, Pk);

  // finalize (mean, rstd) per token for Q and K
  stats_fin<<<dim3(256, 2), 256, 0, stream>>>(Pq, Pk, Sq, Sk);

  // attention (normalization applied on the fly): attn -> d_out tail, ctx -> ws
  attn_kernel<<<4096, 256, 0, stream>>>(Q, KV, KV + 512, Sq, Sk, gq, bq, gk, bk,
                                        out + 33554432, CTX);

  // y_new = y + ctx @ Wout^T + bout (overwrites all d_out scratch)
  gemm_bt<1, 0><<<dim3(512, 4), 256, 0, stream>>>(CTX, WOB, nullptr, out, y, bout,
                                                  512, nullptr);
}